// Round 4
// baseline (638.820 us; speedup 1.0000x reference)
//
#include <hip/hip_runtime.h>
#include <hip/hip_bf16.h>

#define N_NODES 100000
#define N_EDGES 1250000
#define D_FEAT  64
#define SB_NODES 512
#define SB_SHIFT 9
#define NSB     196            // ceil(100000/512) super-buckets
#define CAP_SB  7040           // mean 6400, sd 80 -> +8 sigma (28160B, uint4-aligned)
#define OVF_CAP 8192
#define EPB_I4  1024           // int4 edge-loads per build block (4096 edges)
#define N_I4    (N_EDGES / 4)  // 312500
#define NBLK_BUILD ((N_I4 + EPB_I4 - 1) / EPB_I4)   // 306

__device__ __forceinline__ uint bf16r(float f) {
    uint u = __float_as_uint(f);
    u += 0x7FFFu + ((u >> 16) & 1u);
    return u >> 16;
}

// ---- Pass 0: x -> bf16, rows stored 8x8-TRANSPOSED; block 0 zeroes fill. ----
// stored position p holds feature f(p) = (p&7)*8 + (p>>3).
// => gather lane l8 loads uint4 #l8 and holds features {l8, l8+8, ..., l8+56}.
__global__ __launch_bounds__(256) void to_bf16(
    const float* __restrict__ x, ushort* __restrict__ xh, uint* __restrict__ fill)
{
    if (blockIdx.x == 0 && threadIdx.x < NSB + 2) fill[threadIdx.x] = 0u;
    int r = blockIdx.x * 256 + threadIdx.x;          // one row per thread
    if (r >= N_NODES) return;
    const float4* x4 = (const float4*)x;
    uint4* o4 = (uint4*)xh;
    float v[64];
#pragma unroll
    for (int k = 0; k < 16; ++k) {
        float4 a = x4[(size_t)r * 16 + k];
        v[4 * k + 0] = a.x; v[4 * k + 1] = a.y;
        v[4 * k + 2] = a.z; v[4 * k + 3] = a.w;
    }
#pragma unroll
    for (int q = 0; q < 8; ++q) {                    // uint4 q = words 4q..4q+3
        uint wds[4];
#pragma unroll
        for (int m = 0; m < 4; ++m) {
            int w = 4 * q + m;                       // word index 0..31
            int f0 = ((2 * w) & 7) * 8 + (w >> 2);   // feature of low half
            wds[m] = bf16r(v[f0]) | (bf16r(v[f0 + 8]) << 16);
        }
        o4[(size_t)r * 8 + q] = make_uint4(wds[0], wds[1], wds[2], wds[3]);
    }
}

// ---- Pass 1: coarse partition into 196 super-buckets of 512 nodes. ----
// word = (dstLocal9 << 17) | src17; bucket-ordered LDS stage -> coalesced writeout.
__global__ __launch_bounds__(256) void build_sb(
    const int* __restrict__ src, const int* __restrict__ dst,
    uint* __restrict__ fill, uint* __restrict__ pairs,
    uint* __restrict__ ovfCnt, int2* __restrict__ ovf)
{
    __shared__ uint cnt[256];
    __shared__ uint scn[256];
    __shared__ uint sbase[NSB];
    __shared__ uint   stw[EPB_I4 * 4];   // 16 KB
    __shared__ ushort stb[EPB_I4 * 4];   // 8 KB

    const int t = threadIdx.x;
    cnt[t] = 0;
    __syncthreads();

    uint   pw[16];
    ushort pb[16];
    ushort pr[16];
    bool   vk[4];
    const int i40 = blockIdx.x * EPB_I4;
#pragma unroll
    for (int k = 0; k < 4; ++k) {
        int i4 = i40 + t + k * 256;
        vk[k] = (i4 < N_I4);
        if (vk[k]) {
            int4 d4 = ((const int4*)dst)[i4];
            int4 s4 = ((const int4*)src)[i4];
            int dd[4] = {d4.x, d4.y, d4.z, d4.w};
            int ss[4] = {s4.x, s4.y, s4.z, s4.w};
#pragma unroll
            for (int j = 0; j < 4; ++j) {
                uint b = ((uint)dd[j]) >> SB_SHIFT;
                uint r = atomicAdd(&cnt[b], 1u);
                pw[k * 4 + j] = ((((uint)dd[j]) & (SB_NODES - 1u)) << 17) | (uint)ss[j];
                pb[k * 4 + j] = (ushort)b;
                pr[k * 4 + j] = (ushort)r;
            }
        }
    }
    __syncthreads();

    if (t < NSB) {
        uint c = cnt[t];
        sbase[t] = c ? atomicAdd(&fill[t], c) : 0u;
    }

    scn[t] = cnt[t];
    __syncthreads();
#pragma unroll
    for (int off = 1; off < 256; off <<= 1) {
        uint v = (t >= off) ? scn[t - off] : 0u;
        __syncthreads();
        scn[t] += v;
        __syncthreads();
    }

#pragma unroll
    for (int j = 0; j < 16; ++j) {
        if (vk[j >> 2]) {
            uint b = pb[j];
            uint p = scn[b] - cnt[b] + pr[j];
            stw[p] = pw[j];
            stb[p] = (ushort)b;
        }
    }
    __syncthreads();

    const int m = (int)scn[255];
    for (int j = t; j < m; j += 256) {
        uint w = stw[j];
        uint b = stb[j];
        uint local = (uint)j - (scn[b] - cnt[b]);
        uint g = sbase[b] + local;
        if (g < CAP_SB) {
            pairs[(size_t)b * CAP_SB + g] = w;
        } else {
            uint o = atomicAdd(ovfCnt, 1u);
            if (o < OVF_CAP)
                ovf[o] = make_int2((int)(w & 0x1FFFFu),
                                   (int)((b << SB_SHIFT) | (w >> 17)));
        }
    }
}

// ---- Pass 2 (fused repart+gather): one block per SB, LDS f32 accumulator. ----
// Native ds_add_f32 via unsafeAtomicAdd (CAS-loop killer).
// Rotation layout: acc_pos(dl, f) = dl*64 + ((f + 8*dl) & 63) -> ~2 lanes/bank.
__device__ __forceinline__ void accum_edge(float* __restrict__ acc,
                                           uint w, uint4 cv, int l8)
{
    int dl = (int)(w >> 17);
    float* ab = &acc[dl * D_FEAT];
    int o = (l8 + 8 * dl) & 63;                      // slot of feature l8
    unsafeAtomicAdd(&ab[o],             __uint_as_float((cv.x & 0xFFFFu) << 16));
    unsafeAtomicAdd(&ab[(o +  8) & 63], __uint_as_float(cv.x & 0xFFFF0000u));
    unsafeAtomicAdd(&ab[(o + 16) & 63], __uint_as_float((cv.y & 0xFFFFu) << 16));
    unsafeAtomicAdd(&ab[(o + 24) & 63], __uint_as_float(cv.y & 0xFFFF0000u));
    unsafeAtomicAdd(&ab[(o + 32) & 63], __uint_as_float((cv.z & 0xFFFFu) << 16));
    unsafeAtomicAdd(&ab[(o + 40) & 63], __uint_as_float(cv.z & 0xFFFF0000u));
    unsafeAtomicAdd(&ab[(o + 48) & 63], __uint_as_float((cv.w & 0xFFFFu) << 16));
    unsafeAtomicAdd(&ab[(o + 56) & 63], __uint_as_float(cv.w & 0xFFFF0000u));
}

__global__ __launch_bounds__(1024) void gather_sb(
    const ushort* __restrict__ xh, const uint* __restrict__ pairs,
    const uint* __restrict__ fill, const float* __restrict__ x,
    const int2* __restrict__ ovf, const uint* __restrict__ ovfCnt,
    float* __restrict__ out)
{
    __shared__ float acc[SB_NODES * D_FEAT];         // 131072 B exactly
    const int t   = threadIdx.x;
    const int sb  = blockIdx.x;
    const int g   = t >> 3;                          // edge-group 0..127
    const int l8  = t & 7;                           // lane within group
    const int n   = min((int)fill[sb], CAP_SB);
    const size_t base = (size_t)sb * CAP_SB;
    const uint4* __restrict__ xrow = (const uint4*)xh;
    const uint4* __restrict__ pr4  = (const uint4*)(pairs + base);

    float4* accv = (float4*)acc;
#pragma unroll
    for (int i = 0; i < (SB_NODES * D_FEAT / 4) / 1024; ++i)   // 8
        accv[t + i * 1024] = make_float4(0.f, 0.f, 0.f, 0.f);
    __syncthreads();

    // Batched pipeline: group g owns edges 4g..4g+3 of each 512-edge batch.
    // One uint4 pair-load per batch (broadcast in group, coalesced in wave),
    // 4 row loads issued back-to-back, 1 batch in flight ahead.
    const int NB = n >> 9;                           // full 512-edge batches
    if (NB > 0) {
        uint4 pq = pr4[g];
        uint4 nq = (NB > 1) ? pr4[128 + g] : pq;
        uint4 r0 = xrow[(size_t)(pq.x & 0x1FFFFu) * 8 + l8];
        uint4 r1 = xrow[(size_t)(pq.y & 0x1FFFFu) * 8 + l8];
        uint4 r2 = xrow[(size_t)(pq.z & 0x1FFFFu) * 8 + l8];
        uint4 r3 = xrow[(size_t)(pq.w & 0x1FFFFu) * 8 + l8];
        for (int b = 0; b < NB; ++b) {
            uint4 cq = pq;
            uint4 c0 = r0, c1 = r1, c2 = r2, c3 = r3;
            if (b + 1 < NB) {
                pq = nq;                             // loaded >=1 batch ago
                r0 = xrow[(size_t)(pq.x & 0x1FFFFu) * 8 + l8];
                r1 = xrow[(size_t)(pq.y & 0x1FFFFu) * 8 + l8];
                r2 = xrow[(size_t)(pq.z & 0x1FFFFu) * 8 + l8];
                r3 = xrow[(size_t)(pq.w & 0x1FFFFu) * 8 + l8];
                if (b + 2 < NB) nq = pr4[(size_t)(b + 2) * 128 + g];
            }
            accum_edge(acc, cq.x, c0, l8);
            accum_edge(acc, cq.y, c1, l8);
            accum_edge(acc, cq.z, c2, l8);
            accum_edge(acc, cq.w, c3, l8);
        }
    }
    // remainder (< 512 edges), simple per-edge loop
    for (int e = (NB << 9) + g; e < n; e += 128) {
        uint w = pairs[base + e];
        uint4 v = xrow[(size_t)(w & 0x1FFFFu) * 8 + l8];
        accum_edge(acc, w, v, l8);
    }

    // overflow fixup (normally empty): full-precision adds from x
    const int nov = min((int)*ovfCnt, OVF_CAP);
    for (int e2 = g; e2 < nov; e2 += 128) {
        int2 p = ovf[e2];
        if ((p.y >> SB_SHIFT) == sb) {
            int dl = p.y & (SB_NODES - 1);
            float4 a = ((const float4*)x)[(size_t)p.x * 16 + l8 * 2];
            float4 b = ((const float4*)x)[(size_t)p.x * 16 + l8 * 2 + 1];
            // features 8*l8 .. 8*l8+7 -> slots (8*(l8+dl))&63 .. +7 (no wrap)
            float* ab = &acc[dl * D_FEAT + ((8 * (l8 + dl)) & 63)];
            unsafeAtomicAdd(&ab[0], a.x); unsafeAtomicAdd(&ab[1], a.y);
            unsafeAtomicAdd(&ab[2], a.z); unsafeAtomicAdd(&ab[3], a.w);
            unsafeAtomicAdd(&ab[4], b.x); unsafeAtomicAdd(&ab[5], b.y);
            unsafeAtomicAdd(&ab[6], b.z); unsafeAtomicAdd(&ab[7], b.w);
        }
    }
    __syncthreads();

    // coalesced writeout, unwinding the rotation: quad at slot-pos c holds
    // feature-quad (c - 2*r) & 15 for node r.
    const int nodes_here = min(SB_NODES, N_NODES - sb * SB_NODES);
    float4* out4 = (float4*)out;
    const int lim = nodes_here * 16;
    for (int idx = t; idx < lim; idx += 1024) {
        int r = idx >> 4, c = idx & 15;
        float4 val = *(float4*)&acc[r * D_FEAT + c * 4];
        out4[((size_t)(sb * SB_NODES + r)) * 16 + ((c - 2 * r) & 15)] = val;
    }
}

extern "C" void kernel_launch(void* const* d_in, const int* in_sizes, int n_in,
                              void* d_out, int out_size, void* d_ws, size_t ws_size,
                              hipStream_t stream) {
    const float* x = (const float*)d_in[0];
    const int* edge_index = (const int*)d_in[1];    // [2, N_EDGES] flat int32
    const int* src = edge_index;
    const int* dst = edge_index + N_EDGES;
    float* out = (float*)d_out;

    // ws: xh[12.8MB] | pairs[NSB*CAP_SB u32] | fill[NSB] | ovfCnt+pad | ovf[OVF_CAP int2]
    ushort* xh     = (ushort*)d_ws;
    uint*   pairs  = (uint*)(xh + (size_t)N_NODES * D_FEAT);
    uint*   fill   = pairs + (size_t)NSB * CAP_SB;
    uint*   ovfCnt = fill + NSB;
    int2*   ovf    = (int2*)(fill + NSB + 2);       // even uint offset -> 8B aligned

    to_bf16<<<(N_NODES + 255) / 256, 256, 0, stream>>>(x, xh, fill);     // 391 blocks
    build_sb<<<NBLK_BUILD, 256, 0, stream>>>(src, dst, fill, pairs, ovfCnt, ovf);
    gather_sb<<<NSB, 1024, 0, stream>>>(xh, pairs, fill, x, ovf, ovfCnt, out);
}

// Round 5
// 136.286 us; speedup vs baseline: 4.6874x; 4.6874x over previous
//
#include <hip/hip_runtime.h>
#include <hip/hip_bf16.h>

#define N_NODES 100000
#define N_EDGES 1250000
#define D_FEAT  64
#define SB_NODES 512
#define SB_SHIFT 9
#define NSB     196            // ceil(100000/512) super-buckets
#define CAP_SB  7040           // mean 6400, sd 80 -> +8 sigma (28160B, uint4-aligned)
#define OVF_CAP 8192
#define EPB_I4  1024           // int4 edge-loads per build block (4096 edges)
#define N_I4    (N_EDGES / 4)  // 312500
#define NBLK_BUILD ((N_I4 + EPB_I4 - 1) / EPB_I4)   // 306
#define FXS 65536.f            // Q16 fixed-point scale
#define FXI (1.f / 65536.f)

__device__ __forceinline__ uint bf16r(float f) {
    uint u = __float_as_uint(f);
    u += 0x7FFFu + ((u >> 16) & 1u);
    return u >> 16;
}
__device__ __forceinline__ int fxlo(uint w) {
    return __float2int_rn(__uint_as_float((w & 0xFFFFu) << 16) * FXS);
}
__device__ __forceinline__ int fxhi(uint w) {
    return __float2int_rn(__uint_as_float(w & 0xFFFF0000u) * FXS);
}

// ---- Pass 0: x -> bf16, rows stored 8x8-TRANSPOSED; block 0 zeroes fill. ----
// stored position p holds feature f(p) = (p&7)*8 + (p>>3).
// => gather lane l8 loads uint4 #l8 and holds features {l8, l8+8, ..., l8+56}.
__global__ __launch_bounds__(256) void to_bf16(
    const float* __restrict__ x, ushort* __restrict__ xh, uint* __restrict__ fill)
{
    if (blockIdx.x == 0 && threadIdx.x < NSB + 2) fill[threadIdx.x] = 0u;
    int r = blockIdx.x * 256 + threadIdx.x;          // one row per thread
    if (r >= N_NODES) return;
    const float4* x4 = (const float4*)x;
    uint4* o4 = (uint4*)xh;
    float v[64];
#pragma unroll
    for (int k = 0; k < 16; ++k) {
        float4 a = x4[(size_t)r * 16 + k];
        v[4 * k + 0] = a.x; v[4 * k + 1] = a.y;
        v[4 * k + 2] = a.z; v[4 * k + 3] = a.w;
    }
#pragma unroll
    for (int q = 0; q < 8; ++q) {                    // uint4 q = words 4q..4q+3
        uint wds[4];
#pragma unroll
        for (int m = 0; m < 4; ++m) {
            int w = 4 * q + m;                       // word index 0..31
            int f0 = ((2 * w) & 7) * 8 + (w >> 2);   // feature of low half
            wds[m] = bf16r(v[f0]) | (bf16r(v[f0 + 8]) << 16);
        }
        o4[(size_t)r * 8 + q] = make_uint4(wds[0], wds[1], wds[2], wds[3]);
    }
}

// ---- Pass 1: coarse partition into 196 super-buckets of 512 nodes. ----
// word = (dstLocal9 << 17) | src17; bucket-ordered LDS stage -> coalesced writeout.
__global__ __launch_bounds__(256) void build_sb(
    const int* __restrict__ src, const int* __restrict__ dst,
    uint* __restrict__ fill, uint* __restrict__ pairs,
    uint* __restrict__ ovfCnt, int2* __restrict__ ovf)
{
    __shared__ uint cnt[256];
    __shared__ uint scn[256];
    __shared__ uint sbase[NSB];
    __shared__ uint   stw[EPB_I4 * 4];   // 16 KB
    __shared__ ushort stb[EPB_I4 * 4];   // 8 KB

    const int t = threadIdx.x;
    cnt[t] = 0;
    __syncthreads();

    uint   pw[16];
    ushort pb[16];
    ushort pr[16];
    bool   vk[4];
    const int i40 = blockIdx.x * EPB_I4;
#pragma unroll
    for (int k = 0; k < 4; ++k) {
        int i4 = i40 + t + k * 256;
        vk[k] = (i4 < N_I4);
        if (vk[k]) {
            int4 d4 = ((const int4*)dst)[i4];
            int4 s4 = ((const int4*)src)[i4];
            int dd[4] = {d4.x, d4.y, d4.z, d4.w};
            int ss[4] = {s4.x, s4.y, s4.z, s4.w};
#pragma unroll
            for (int j = 0; j < 4; ++j) {
                uint b = ((uint)dd[j]) >> SB_SHIFT;
                uint r = atomicAdd(&cnt[b], 1u);
                pw[k * 4 + j] = ((((uint)dd[j]) & (SB_NODES - 1u)) << 17) | (uint)ss[j];
                pb[k * 4 + j] = (ushort)b;
                pr[k * 4 + j] = (ushort)r;
            }
        }
    }
    __syncthreads();

    if (t < NSB) {
        uint c = cnt[t];
        sbase[t] = c ? atomicAdd(&fill[t], c) : 0u;
    }

    scn[t] = cnt[t];
    __syncthreads();
#pragma unroll
    for (int off = 1; off < 256; off <<= 1) {
        uint v = (t >= off) ? scn[t - off] : 0u;
        __syncthreads();
        scn[t] += v;
        __syncthreads();
    }

#pragma unroll
    for (int j = 0; j < 16; ++j) {
        if (vk[j >> 2]) {
            uint b = pb[j];
            uint p = scn[b] - cnt[b] + pr[j];
            stw[p] = pw[j];
            stb[p] = (ushort)b;
        }
    }
    __syncthreads();

    const int m = (int)scn[255];
    for (int j = t; j < m; j += 256) {
        uint w = stw[j];
        uint b = stb[j];
        uint local = (uint)j - (scn[b] - cnt[b]);
        uint g = sbase[b] + local;
        if (g < CAP_SB) {
            pairs[(size_t)b * CAP_SB + g] = w;
        } else {
            uint o = atomicAdd(ovfCnt, 1u);
            if (o < OVF_CAP)
                ovf[o] = make_int2((int)(w & 0x1FFFFu),
                                   (int)((b << SB_SHIFT) | (w >> 17)));
        }
    }
}

// ---- Pass 2 (fused repart+gather): one block per SB, LDS Q16 int accumulator. ----
// Integer atomicAdd directly on the __shared__ array -> native ds_add_u32
// (same pattern as build_sb's cnt[] atomics, proven fast).
// Rotation layout: acc_pos(dl, f) = dl*64 + ((f + 8*dl) & 63) -> ~2 lanes/bank.
#define ACCUM_EDGE(W, CV)                                              \
    do {                                                               \
        int dl_ = (int)((W) >> 17);                                    \
        int ob_ = dl_ * D_FEAT;                                        \
        int o_  = (l8 + 8 * dl_) & 63;                                 \
        atomicAdd(&acc[ob_ + o_],               fxlo((CV).x));         \
        atomicAdd(&acc[ob_ + ((o_ +  8) & 63)], fxhi((CV).x));         \
        atomicAdd(&acc[ob_ + ((o_ + 16) & 63)], fxlo((CV).y));         \
        atomicAdd(&acc[ob_ + ((o_ + 24) & 63)], fxhi((CV).y));         \
        atomicAdd(&acc[ob_ + ((o_ + 32) & 63)], fxlo((CV).z));         \
        atomicAdd(&acc[ob_ + ((o_ + 40) & 63)], fxhi((CV).z));         \
        atomicAdd(&acc[ob_ + ((o_ + 48) & 63)], fxlo((CV).w));         \
        atomicAdd(&acc[ob_ + ((o_ + 56) & 63)], fxhi((CV).w));         \
    } while (0)

__global__ __launch_bounds__(1024) void gather_sb(
    const ushort* __restrict__ xh, const uint* __restrict__ pairs,
    const uint* __restrict__ fill, const float* __restrict__ x,
    const int2* __restrict__ ovf, const uint* __restrict__ ovfCnt,
    float* __restrict__ out)
{
    __shared__ int acc[SB_NODES * D_FEAT];           // 131072 B exactly
    const int t   = threadIdx.x;
    const int sb  = blockIdx.x;
    const int g   = t >> 3;                          // edge-group 0..127
    const int l8  = t & 7;                           // lane within group
    const int n   = min((int)fill[sb], CAP_SB);
    const size_t base = (size_t)sb * CAP_SB;
    const uint4* __restrict__ xrow = (const uint4*)xh;
    const uint4* __restrict__ pr4  = (const uint4*)(pairs + base);

    int4* accv = (int4*)acc;
#pragma unroll
    for (int i = 0; i < (SB_NODES * D_FEAT / 4) / 1024; ++i)   // 8
        accv[t + i * 1024] = make_int4(0, 0, 0, 0);
    __syncthreads();

    // Batched pipeline: group g owns edges 4g..4g+3 of each 512-edge batch.
    // One uint4 pair-load per batch, 4 row loads back-to-back, 1 batch ahead.
    const int NB = n >> 9;                           // full 512-edge batches
    if (NB > 0) {
        uint4 pq = pr4[g];
        uint4 nq = (NB > 1) ? pr4[128 + g] : pq;
        uint4 r0 = xrow[(size_t)(pq.x & 0x1FFFFu) * 8 + l8];
        uint4 r1 = xrow[(size_t)(pq.y & 0x1FFFFu) * 8 + l8];
        uint4 r2 = xrow[(size_t)(pq.z & 0x1FFFFu) * 8 + l8];
        uint4 r3 = xrow[(size_t)(pq.w & 0x1FFFFu) * 8 + l8];
        for (int b = 0; b < NB; ++b) {
            uint4 cq = pq;
            uint4 c0 = r0, c1 = r1, c2 = r2, c3 = r3;
            if (b + 1 < NB) {
                pq = nq;                             // loaded >=1 batch ago
                r0 = xrow[(size_t)(pq.x & 0x1FFFFu) * 8 + l8];
                r1 = xrow[(size_t)(pq.y & 0x1FFFFu) * 8 + l8];
                r2 = xrow[(size_t)(pq.z & 0x1FFFFu) * 8 + l8];
                r3 = xrow[(size_t)(pq.w & 0x1FFFFu) * 8 + l8];
                if (b + 2 < NB) nq = pr4[(size_t)(b + 2) * 128 + g];
            }
            ACCUM_EDGE(cq.x, c0);
            ACCUM_EDGE(cq.y, c1);
            ACCUM_EDGE(cq.z, c2);
            ACCUM_EDGE(cq.w, c3);
        }
    }
    // remainder (< 512 edges), simple per-edge loop
    for (int e = (NB << 9) + g; e < n; e += 128) {
        uint w = pairs[base + e];
        uint4 v = xrow[(size_t)(w & 0x1FFFFu) * 8 + l8];
        ACCUM_EDGE(w, v);
    }

    // overflow fixup (normally empty): full-precision adds from x, Q16
    const int nov = min((int)*ovfCnt, OVF_CAP);
    for (int e2 = g; e2 < nov; e2 += 128) {
        int2 p = ovf[e2];
        if ((p.y >> SB_SHIFT) == sb) {
            int dl = p.y & (SB_NODES - 1);
            float4 a = ((const float4*)x)[(size_t)p.x * 16 + l8 * 2];
            float4 b = ((const float4*)x)[(size_t)p.x * 16 + l8 * 2 + 1];
            // features 8*l8 .. 8*l8+7 -> slots (8*(l8+dl))&63 .. +7 (no wrap)
            int bi = dl * D_FEAT + ((8 * (l8 + dl)) & 63);
            atomicAdd(&acc[bi + 0], __float2int_rn(a.x * FXS));
            atomicAdd(&acc[bi + 1], __float2int_rn(a.y * FXS));
            atomicAdd(&acc[bi + 2], __float2int_rn(a.z * FXS));
            atomicAdd(&acc[bi + 3], __float2int_rn(a.w * FXS));
            atomicAdd(&acc[bi + 4], __float2int_rn(b.x * FXS));
            atomicAdd(&acc[bi + 5], __float2int_rn(b.y * FXS));
            atomicAdd(&acc[bi + 6], __float2int_rn(b.z * FXS));
            atomicAdd(&acc[bi + 7], __float2int_rn(b.w * FXS));
        }
    }
    __syncthreads();

    // coalesced writeout, unwinding the rotation: quad at slot-pos c holds
    // feature-quad (c - 2*r) & 15 for node r.
    const int nodes_here = min(SB_NODES, N_NODES - sb * SB_NODES);
    float4* out4 = (float4*)out;
    const int lim = nodes_here * 16;
    for (int idx = t; idx < lim; idx += 1024) {
        int r = idx >> 4, c = idx & 15;
        int4 iv = *(int4*)&acc[r * D_FEAT + c * 4];
        out4[((size_t)(sb * SB_NODES + r)) * 16 + ((c - 2 * r) & 15)] =
            make_float4(iv.x * FXI, iv.y * FXI, iv.z * FXI, iv.w * FXI);
    }
}

extern "C" void kernel_launch(void* const* d_in, const int* in_sizes, int n_in,
                              void* d_out, int out_size, void* d_ws, size_t ws_size,
                              hipStream_t stream) {
    const float* x = (const float*)d_in[0];
    const int* edge_index = (const int*)d_in[1];    // [2, N_EDGES] flat int32
    const int* src = edge_index;
    const int* dst = edge_index + N_EDGES;
    float* out = (float*)d_out;

    // ws: xh[12.8MB] | pairs[NSB*CAP_SB u32] | fill[NSB] | ovfCnt+pad | ovf[OVF_CAP int2]
    ushort* xh     = (ushort*)d_ws;
    uint*   pairs  = (uint*)(xh + (size_t)N_NODES * D_FEAT);
    uint*   fill   = pairs + (size_t)NSB * CAP_SB;
    uint*   ovfCnt = fill + NSB;
    int2*   ovf    = (int2*)(fill + NSB + 2);       // even uint offset -> 8B aligned

    to_bf16<<<(N_NODES + 255) / 256, 256, 0, stream>>>(x, xh, fill);     // 391 blocks
    build_sb<<<NBLK_BUILD, 256, 0, stream>>>(src, dst, fill, pairs, ovfCnt, ovf);
    gather_sb<<<NSB, 1024, 0, stream>>>(xh, pairs, fill, x, ovf, ovfCnt, out);
}

// Round 6
// 135.658 us; speedup vs baseline: 4.7091x; 1.0046x over previous
//
#include <hip/hip_runtime.h>
#include <hip/hip_bf16.h>

#define N_NODES 100000
#define N_EDGES 1250000
#define D_FEAT  64
#define SB_NODES 512
#define SB_SHIFT 9
#define NSB     196            // ceil(100000/512) super-buckets
#define CAP_SB  7040           // mean 6400, sd 80 -> +8 sigma (28160B, uint4-aligned)
#define OVF_CAP 8192
#define EPB_I4  512            // int4 edge-loads per build block (2048 edges)
#define N_I4    (N_EDGES / 4)  // 312500
#define NBLK_BUILD ((N_I4 + EPB_I4 - 1) / EPB_I4)   // 611
#define NBLK_BF16  ((N_NODES + 255) / 256)          // 391
#define FXS 65536.f            // Q16 fixed-point scale
#define FXI (1.f / 65536.f)

__device__ __forceinline__ uint bf16r(float f) {
    uint u = __float_as_uint(f);
    u += 0x7FFFu + ((u >> 16) & 1u);
    return u >> 16;
}
__device__ __forceinline__ int fxlo(uint w) {
    return __float2int_rn(__uint_as_float((w & 0xFFFFu) << 16) * FXS);
}
__device__ __forceinline__ int fxhi(uint w) {
    return __float2int_rn(__uint_as_float(w & 0xFFFF0000u) * FXS);
}

// ---- Fused prep: blocks [0, NBLK_BUILD) partition edges; the rest convert x.
// Roles are independent (disjoint in/out); fusing lets the BW-streaming bf16
// work hide the latency-bound build work. fill/ovfCnt zeroed by hipMemsetAsync.
__global__ __launch_bounds__(256) void prep(
    const float* __restrict__ x, ushort* __restrict__ xh,
    const int* __restrict__ src, const int* __restrict__ dst,
    uint* __restrict__ fill, uint* __restrict__ pairs,
    uint* __restrict__ ovfCnt, int2* __restrict__ ovf)
{
    __shared__ uint cnt[256];
    __shared__ uint scn[256];
    __shared__ uint sbase[NSB];
    __shared__ uint   stw[EPB_I4 * 4];   // 8 KB
    __shared__ ushort stb[EPB_I4 * 4];   // 4 KB

    const int t = threadIdx.x;

    if (blockIdx.x >= NBLK_BUILD) {
        // ---- to_bf16 role: rows stored 8x8-TRANSPOSED. ----
        // stored position p holds feature f(p) = (p&7)*8 + (p>>3).
        int r = (blockIdx.x - NBLK_BUILD) * 256 + t;     // one row per thread
        if (r >= N_NODES) return;
        const float4* x4 = (const float4*)x;
        uint4* o4 = (uint4*)xh;
        float v[64];
#pragma unroll
        for (int k = 0; k < 16; ++k) {
            float4 a = x4[(size_t)r * 16 + k];
            v[4 * k + 0] = a.x; v[4 * k + 1] = a.y;
            v[4 * k + 2] = a.z; v[4 * k + 3] = a.w;
        }
#pragma unroll
        for (int q = 0; q < 8; ++q) {                    // uint4 q = words 4q..4q+3
            uint wds[4];
#pragma unroll
            for (int m = 0; m < 4; ++m) {
                int w = 4 * q + m;                       // word index 0..31
                int f0 = ((2 * w) & 7) * 8 + (w >> 2);   // feature of low half
                wds[m] = bf16r(v[f0]) | (bf16r(v[f0 + 8]) << 16);
            }
            o4[(size_t)r * 8 + q] = make_uint4(wds[0], wds[1], wds[2], wds[3]);
        }
        return;
    }

    // ---- build role: partition 2048 edges into 196 super-buckets. ----
    // word = (dstLocal9 << 17) | src17; bucket-ordered LDS stage -> coalesced out.
    cnt[t] = 0;
    __syncthreads();

    uint   pw[8];
    ushort pb[8];
    ushort pr[8];
    bool   vk[2];
    const int i40 = blockIdx.x * EPB_I4;
#pragma unroll
    for (int k = 0; k < 2; ++k) {
        int i4 = i40 + t + k * 256;
        vk[k] = (i4 < N_I4);
        if (vk[k]) {
            int4 d4 = ((const int4*)dst)[i4];
            int4 s4 = ((const int4*)src)[i4];
            int dd[4] = {d4.x, d4.y, d4.z, d4.w};
            int ss[4] = {s4.x, s4.y, s4.z, s4.w};
#pragma unroll
            for (int j = 0; j < 4; ++j) {
                uint b = ((uint)dd[j]) >> SB_SHIFT;
                uint r = atomicAdd(&cnt[b], 1u);
                pw[k * 4 + j] = ((((uint)dd[j]) & (SB_NODES - 1u)) << 17) | (uint)ss[j];
                pb[k * 4 + j] = (ushort)b;
                pr[k * 4 + j] = (ushort)r;
            }
        }
    }
    __syncthreads();

    if (t < NSB) {
        uint c = cnt[t];
        sbase[t] = c ? atomicAdd(&fill[t], c) : 0u;
    }

    scn[t] = cnt[t];
    __syncthreads();
#pragma unroll
    for (int off = 1; off < 256; off <<= 1) {
        uint v = (t >= off) ? scn[t - off] : 0u;
        __syncthreads();
        scn[t] += v;
        __syncthreads();
    }

#pragma unroll
    for (int j = 0; j < 8; ++j) {
        if (vk[j >> 2]) {
            uint b = pb[j];
            uint p = scn[b] - cnt[b] + pr[j];
            stw[p] = pw[j];
            stb[p] = (ushort)b;
        }
    }
    __syncthreads();

    const int m = (int)scn[255];
    for (int j = t; j < m; j += 256) {
        uint w = stw[j];
        uint b = stb[j];
        uint local = (uint)j - (scn[b] - cnt[b]);
        uint g = sbase[b] + local;
        if (g < CAP_SB) {
            pairs[(size_t)b * CAP_SB + g] = w;
        } else {
            uint o = atomicAdd(ovfCnt, 1u);
            if (o < OVF_CAP)
                ovf[o] = make_int2((int)(w & 0x1FFFFu),
                                   (int)((b << SB_SHIFT) | (w >> 17)));
        }
    }
}

// ---- Gather (unchanged from R5, harness-verified): one block per SB,
// LDS Q16 int accumulator, native ds_add_u32.
// Rotation layout: acc_pos(dl, f) = dl*64 + ((f + 8*dl) & 63) -> ~2 lanes/bank.
#define ACCUM_EDGE(W, CV)                                              \
    do {                                                               \
        int dl_ = (int)((W) >> 17);                                    \
        int ob_ = dl_ * D_FEAT;                                        \
        int o_  = (l8 + 8 * dl_) & 63;                                 \
        atomicAdd(&acc[ob_ + o_],               fxlo((CV).x));         \
        atomicAdd(&acc[ob_ + ((o_ +  8) & 63)], fxhi((CV).x));         \
        atomicAdd(&acc[ob_ + ((o_ + 16) & 63)], fxlo((CV).y));         \
        atomicAdd(&acc[ob_ + ((o_ + 24) & 63)], fxhi((CV).y));         \
        atomicAdd(&acc[ob_ + ((o_ + 32) & 63)], fxlo((CV).z));         \
        atomicAdd(&acc[ob_ + ((o_ + 40) & 63)], fxhi((CV).z));         \
        atomicAdd(&acc[ob_ + ((o_ + 48) & 63)], fxlo((CV).w));         \
        atomicAdd(&acc[ob_ + ((o_ + 56) & 63)], fxhi((CV).w));         \
    } while (0)

__global__ __launch_bounds__(1024) void gather_sb(
    const ushort* __restrict__ xh, const uint* __restrict__ pairs,
    const uint* __restrict__ fill, const float* __restrict__ x,
    const int2* __restrict__ ovf, const uint* __restrict__ ovfCnt,
    float* __restrict__ out)
{
    __shared__ int acc[SB_NODES * D_FEAT];           // 131072 B exactly
    const int t   = threadIdx.x;
    const int sb  = blockIdx.x;
    const int g   = t >> 3;                          // edge-group 0..127
    const int l8  = t & 7;                           // lane within group
    const int n   = min((int)fill[sb], CAP_SB);
    const size_t base = (size_t)sb * CAP_SB;
    const uint4* __restrict__ xrow = (const uint4*)xh;
    const uint4* __restrict__ pr4  = (const uint4*)(pairs + base);

    int4* accv = (int4*)acc;
#pragma unroll
    for (int i = 0; i < (SB_NODES * D_FEAT / 4) / 1024; ++i)   // 8
        accv[t + i * 1024] = make_int4(0, 0, 0, 0);
    __syncthreads();

    // Batched pipeline: group g owns edges 4g..4g+3 of each 512-edge batch.
    // One uint4 pair-load per batch, 4 row loads back-to-back, 1 batch ahead.
    const int NB = n >> 9;                           // full 512-edge batches
    if (NB > 0) {
        uint4 pq = pr4[g];
        uint4 nq = (NB > 1) ? pr4[128 + g] : pq;
        uint4 r0 = xrow[(size_t)(pq.x & 0x1FFFFu) * 8 + l8];
        uint4 r1 = xrow[(size_t)(pq.y & 0x1FFFFu) * 8 + l8];
        uint4 r2 = xrow[(size_t)(pq.z & 0x1FFFFu) * 8 + l8];
        uint4 r3 = xrow[(size_t)(pq.w & 0x1FFFFu) * 8 + l8];
        for (int b = 0; b < NB; ++b) {
            uint4 cq = pq;
            uint4 c0 = r0, c1 = r1, c2 = r2, c3 = r3;
            if (b + 1 < NB) {
                pq = nq;                             // loaded >=1 batch ago
                r0 = xrow[(size_t)(pq.x & 0x1FFFFu) * 8 + l8];
                r1 = xrow[(size_t)(pq.y & 0x1FFFFu) * 8 + l8];
                r2 = xrow[(size_t)(pq.z & 0x1FFFFu) * 8 + l8];
                r3 = xrow[(size_t)(pq.w & 0x1FFFFu) * 8 + l8];
                if (b + 2 < NB) nq = pr4[(size_t)(b + 2) * 128 + g];
            }
            ACCUM_EDGE(cq.x, c0);
            ACCUM_EDGE(cq.y, c1);
            ACCUM_EDGE(cq.z, c2);
            ACCUM_EDGE(cq.w, c3);
        }
    }
    // remainder (< 512 edges), simple per-edge loop
    for (int e = (NB << 9) + g; e < n; e += 128) {
        uint w = pairs[base + e];
        uint4 v = xrow[(size_t)(w & 0x1FFFFu) * 8 + l8];
        ACCUM_EDGE(w, v);
    }

    // overflow fixup (normally empty): full-precision adds from x, Q16
    const int nov = min((int)*ovfCnt, OVF_CAP);
    for (int e2 = g; e2 < nov; e2 += 128) {
        int2 p = ovf[e2];
        if ((p.y >> SB_SHIFT) == sb) {
            int dl = p.y & (SB_NODES - 1);
            float4 a = ((const float4*)x)[(size_t)p.x * 16 + l8 * 2];
            float4 b = ((const float4*)x)[(size_t)p.x * 16 + l8 * 2 + 1];
            // features 8*l8 .. 8*l8+7 -> slots (8*(l8+dl))&63 .. +7 (no wrap)
            int bi = dl * D_FEAT + ((8 * (l8 + dl)) & 63);
            atomicAdd(&acc[bi + 0], __float2int_rn(a.x * FXS));
            atomicAdd(&acc[bi + 1], __float2int_rn(a.y * FXS));
            atomicAdd(&acc[bi + 2], __float2int_rn(a.z * FXS));
            atomicAdd(&acc[bi + 3], __float2int_rn(a.w * FXS));
            atomicAdd(&acc[bi + 4], __float2int_rn(b.x * FXS));
            atomicAdd(&acc[bi + 5], __float2int_rn(b.y * FXS));
            atomicAdd(&acc[bi + 6], __float2int_rn(b.z * FXS));
            atomicAdd(&acc[bi + 7], __float2int_rn(b.w * FXS));
        }
    }
    __syncthreads();

    // coalesced writeout, unwinding the rotation: quad at slot-pos c holds
    // feature-quad (c - 2*r) & 15 for node r.
    const int nodes_here = min(SB_NODES, N_NODES - sb * SB_NODES);
    float4* out4 = (float4*)out;
    const int lim = nodes_here * 16;
    for (int idx = t; idx < lim; idx += 1024) {
        int r = idx >> 4, c = idx & 15;
        int4 iv = *(int4*)&acc[r * D_FEAT + c * 4];
        out4[((size_t)(sb * SB_NODES + r)) * 16 + ((c - 2 * r) & 15)] =
            make_float4(iv.x * FXI, iv.y * FXI, iv.z * FXI, iv.w * FXI);
    }
}

extern "C" void kernel_launch(void* const* d_in, const int* in_sizes, int n_in,
                              void* d_out, int out_size, void* d_ws, size_t ws_size,
                              hipStream_t stream) {
    const float* x = (const float*)d_in[0];
    const int* edge_index = (const int*)d_in[1];    // [2, N_EDGES] flat int32
    const int* src = edge_index;
    const int* dst = edge_index + N_EDGES;
    float* out = (float*)d_out;

    // ws: xh[12.8MB] | pairs[NSB*CAP_SB u32] | fill[NSB] | ovfCnt+pad | ovf[OVF_CAP int2]
    ushort* xh     = (ushort*)d_ws;
    uint*   pairs  = (uint*)(xh + (size_t)N_NODES * D_FEAT);
    uint*   fill   = pairs + (size_t)NSB * CAP_SB;
    uint*   ovfCnt = fill + NSB;
    int2*   ovf    = (int2*)(fill + NSB + 2);       // even uint offset -> 8B aligned

    hipMemsetAsync(fill, 0, (NSB + 2) * sizeof(uint), stream);   // fill + ovfCnt + pad
    prep<<<NBLK_BUILD + NBLK_BF16, 256, 0, stream>>>(
        x, xh, src, dst, fill, pairs, ovfCnt, ovf);              // 1002 blocks
    gather_sb<<<NSB, 1024, 0, stream>>>(xh, pairs, fill, x, ovf, ovfCnt, out);
}